// Round 22
// baseline (125.946 us; speedup 1.0000x reference)
//
#include <hip/hip_runtime.h>

#define ATTN_SCALE 0.17677669529663687f  // 32^-0.5

typedef __attribute__((ext_vector_type(8))) short bf16x8;
typedef __attribute__((ext_vector_type(4))) float f32x4;
typedef __attribute__((ext_vector_type(16))) float f32x16;

__device__ inline unsigned short f2bf(float x) {
    unsigned int u = __float_as_uint(x);
    unsigned int r = u + 0x7fffu + ((u >> 16) & 1u);
    return (unsigned short)(r >> 16);
}
__device__ inline unsigned int pk2(float lo, float hi) {
    return (unsigned int)f2bf(lo) | ((unsigned int)f2bf(hi) << 16);
}
__device__ inline float bf2f(unsigned int u) { return __uint_as_float(u << 16); }

// async 16B global->LDS (lds dest = wave-uniform base + lane*16)
#define GLDS16(gp, lp) \
    __builtin_amdgcn_global_load_lds((const __attribute__((address_space(1))) void*)(gp), \
                                     (__attribute__((address_space(3))) void*)(lp), 16, 0, 0)

// Stage a (NIT*8 rows per wave) x 64col bf16 tile into LDS (row-major, 64/row),
// XOR slot-swizzled via pre-swizzled GLOBAL address (m173 pattern).
template<int NIT>
__device__ inline void stage_tile_n(const ushort* __restrict__ g, int rstride, int kofs,
                                    ushort* lbase, int w, int lane) {
    const int r0 = w * (NIT * 8);
    #pragma unroll
    for (int u = 0; u < NIT; ++u) {
        const int row  = r0 + u * 8 + (lane >> 3);
        const int slog = (lane & 7) ^ (row & 7);
        GLDS16(g + (size_t)row * rstride + kofs + slog * 8,
               lbase + (size_t)(r0 + u * 8) * 64);
    }
}
__device__ inline void stage_tile(const ushort* __restrict__ g, int rstride, int kofs,
                                  ushort* lbase, int w, int lane) {
    stage_tile_n<4>(g, rstride, kofs, lbase, w, lane);
}

// read one 16B MFMA fragment (8 bf16, k-contig) honoring the swizzle
__device__ inline bf16x8 frag_ld(const ushort* t, int row, int slog) {
    return *(const bf16x8*)(t + row * 64 + ((slog ^ (row & 7)) * 8));
}

// one BK=64 MFMA step: 4x4 16x16 frags per wave, acc[fm][fp]
#define MFMA_STEP(WS_, XS_, WM_, WP_)                                                       \
    _Pragma("unroll")                                                                       \
    for (int kh = 0; kh < 2; ++kh) {                                                        \
        bf16x8 av[4], bvv[4];                                                               \
        _Pragma("unroll")                                                                   \
        for (int fm = 0; fm < 4; ++fm) av[fm]  = frag_ld(WS_, WM_ + fm * 16 + i16, kh * 4 + g); \
        _Pragma("unroll")                                                                   \
        for (int fp = 0; fp < 4; ++fp) bvv[fp] = frag_ld(XS_, WP_ + fp * 16 + i16, kh * 4 + g); \
        _Pragma("unroll")                                                                   \
        for (int fm = 0; fm < 4; ++fm)                                                      \
            _Pragma("unroll")                                                               \
            for (int fp = 0; fp < 4; ++fp)                                                  \
                acc[fm][fp] = __builtin_amdgcn_mfma_f32_16x16x32_bf16(av[fm], bvv[fp],      \
                                                                      acc[fm][fp], 0, 0, 0); \
    }

// ---------------------------------------------------------------------------
// cvt_fused: blocks [0,512) = cvt_x (xbfT + xcol); blocks [512,1344) = cvt_w.
// ---------------------------------------------------------------------------
__global__ __launch_bounds__(256) void cvt_fused(
    const float* __restrict__ x,
    const float* __restrict__ Wq, const float* __restrict__ Wqb,
    const float* __restrict__ Wkvb, const float* __restrict__ Wkv,
    const float* __restrict__ Wout,
    ushort* __restrict__ xbfT, ushort* __restrict__ xcol,
    ushort* __restrict__ Wallb, ushort* __restrict__ Wkvbb, ushort* __restrict__ Woutb)
{
    __shared__ float T[128][65];     // [p-local][c] (cvt_x branch only)
    const int bid = blockIdx.x;
    const int t = threadIdx.x;

    if (bid < 512) {
        // ---------------- cvt_x branch ----------------
        const int i2 = bid & 31;
        const int c0 = ((bid >> 5) & 3) * 64;
        const int bb = bid >> 7;
        const int p0 = i2 * 128;
        const float* xb = x + ((size_t)bb * 256 + c0) * 4096 + p0;

        {   // load 64 channels x 128 pixels, transpose into T[p][c]
            const int cc = t >> 2;
            const int pq = (t & 3) * 32;
            #pragma unroll
            for (int u = 0; u < 8; ++u) {
                const float4 v = *(const float4*)&xb[(size_t)cc * 4096 + pq + u * 4];
                T[pq + u * 4 + 0][cc] = v.x; T[pq + u * 4 + 1][cc] = v.y;
                T[pq + u * 4 + 2][cc] = v.z; T[pq + u * 4 + 3][cc] = v.w;
            }
        }
        __syncthreads();

        {   // emit xbfT
            const int pp = t >> 1, ch = (t & 1) * 32;
            const float* row = &T[pp][ch];
            unsigned int pkv[16];
            #pragma unroll
            for (int u = 0; u < 16; ++u) pkv[u] = pk2(row[2 * u], row[2 * u + 1]);
            ushort* dst = xbfT + ((size_t)bb * 4096 + p0 + pp) * 256 + c0 + ch;
            *(uint4*)&dst[0]  = *(uint4*)&pkv[0];
            *(uint4*)&dst[8]  = *(uint4*)&pkv[4];
            *(uint4*)&dst[16] = *(uint4*)&pkv[8];
            *(uint4*)&dst[24] = *(uint4*)&pkv[12];
        }
        {   // emit xcol
            const int j = t >> 3, c8 = (t & 7) * 8;
            unsigned int pkv[16];
            #pragma unroll
            for (int c = 0; c < 8; ++c) {
                pkv[2 * c]     = pk2(T[2 * j][c8 + c],      T[2 * j + 1][c8 + c]);
                pkv[2 * c + 1] = pk2(T[64 + 2 * j][c8 + c], T[65 + 2 * j][c8 + c]);
            }
            ushort* dst = xcol + ((size_t)bb * 1024 + i2 * 32 + j) * 1024 + (size_t)(c0 + c8) * 4;
            *(uint4*)&dst[0]  = *(uint4*)&pkv[0];
            *(uint4*)&dst[8]  = *(uint4*)&pkv[4];
            *(uint4*)&dst[16] = *(uint4*)&pkv[8];
            *(uint4*)&dst[24] = *(uint4*)&pkv[12];
        }
    } else {
        // ---------------- cvt_w branch ----------------
        const int id = (bid - 512) * 256 + t;   // float4-chunk id
        const float* src; ushort* dst;
        if (id < 65536) {
            const int m = id >> 6, c4 = (id & 63) * 4;
            src = (m < 256) ? &Wq[(size_t)m * 256 + c4]
                : (m < 512) ? &Wqb[(size_t)(m - 256) * 256 + c4]
                            : &Wkvb[(size_t)(m - 512) * 256 + c4];
            dst = Wallb + (size_t)id * 4;
        } else if (id < 65536 + 131072) {
            const size_t el = (size_t)(id - 65536) * 4;
            src = &Wkv[el]; dst = Wkvbb + el;
        } else {
            const size_t el = (size_t)(id - 65536 - 131072) * 4;
            src = &Wout[el]; dst = Woutb + el;
        }
        const float4 v = *(const float4*)src;
        ushort4 o; o.x = f2bf(v.x); o.y = f2bf(v.y); o.z = f2bf(v.z); o.w = f2bf(v.w);
        *(ushort4*)dst = o;
    }
}

// ---------------------------------------------------------------------------
// projconv_fused: blocks [0,1024) = proj_mfma; [1024,1280) = conv_mfma.
// ---------------------------------------------------------------------------
__global__ __launch_bounds__(256) void projconv_fused(
    const ushort* __restrict__ Wallb, const ushort* __restrict__ xbfT,
    const ushort* __restrict__ Wkvbb, const ushort* __restrict__ xcol,
    ushort* __restrict__ qTb, ushort* __restrict__ qbT, ushort* __restrict__ kvbT,
    ushort* __restrict__ kTb, ushort* __restrict__ vTtb)
{
    __shared__ __align__(16) ushort lds[16384];
    const int bid = blockIdx.x;
    const int tid = threadIdx.x, lane = tid & 63, w = tid >> 6;
    const int g = lane >> 4, i16 = lane & 15;

    if (bid < 1024) {
        // ---------------- proj branch ----------------
        ushort* Ws = lds; ushort* Xs = lds + 8192;
        const int p0 = (bid & 31) * 128, m0 = ((bid >> 5) & 7) * 128, bb = bid >> 8;
        const int wm = (w >> 1) * 64, wp = (w & 1) * 64;
        const ushort* Ag = Wallb + (size_t)m0 * 256;
        const ushort* Bg = xbfT + ((size_t)bb * 4096 + p0) * 256;
        f32x4 acc[4][4] = {};
        for (int ks = 0; ks < 4; ++ks) {
            stage_tile(Ag, 256, ks * 64, Ws, w, lane);
            stage_tile(Bg, 256, ks * 64, Xs, w, lane);
            __syncthreads();
            MFMA_STEP(Ws, Xs, wm, wp);
            __syncthreads();
        }
        #pragma unroll
        for (int fp = 0; fp < 4; ++fp) {
            const int p = p0 + wp + fp * 16 + i16;
            #pragma unroll
            for (int fm = 0; fm < 4; ++fm) {
                const int m = m0 + wm + fm * 16 + 4 * g;
                if (m0 < 256) {
                    ushort4 v;
                    v.x = f2bf(acc[fm][fp][0] * ATTN_SCALE); v.y = f2bf(acc[fm][fp][1] * ATTN_SCALE);
                    v.z = f2bf(acc[fm][fp][2] * ATTN_SCALE); v.w = f2bf(acc[fm][fp][3] * ATTN_SCALE);
                    *(ushort4*)&qTb[((size_t)bb * 4096 + p) * 256 + m] = v;
                } else if (m0 < 512) {
                    ushort4 v;
                    v.x = f2bf(acc[fm][fp][0]); v.y = f2bf(acc[fm][fp][1]);
                    v.z = f2bf(acc[fm][fp][2]); v.w = f2bf(acc[fm][fp][3]);
                    *(ushort4*)&qbT[((size_t)bb * 4096 + p) * 256 + (m - 256)] = v;
                } else {
                    ushort4 v;
                    v.x = f2bf(acc[fm][fp][0]); v.y = f2bf(acc[fm][fp][1]);
                    v.z = f2bf(acc[fm][fp][2]); v.w = f2bf(acc[fm][fp][3]);
                    *(ushort4*)&kvbT[((size_t)bb * 4096 + p) * 512 + (m - 512)] = v;
                }
            }
        }
    } else {
        // ---------------- conv branch ----------------
        ushort* Ws = lds;          // 64 rows x 64
        ushort* Xs = lds + 4096;   // 128 rows x 64
        const int id = bid - 1024;
        const int pp0 = (id & 7) * 128, m0 = ((id >> 3) & 7) * 64, bb = id >> 6;
        const int wm = (w >> 1) * 32, wp = (w & 1) * 64;
        const ushort* Ag = Wkvbb + (size_t)m0 * 1024;
        const ushort* Bg = xcol + ((size_t)bb * 1024 + pp0) * 1024;
        f32x4 acc[2][4] = {};
        for (int ks = 0; ks < 16; ++ks) {
            stage_tile_n<2>(Ag, 1024, ks * 64, Ws, w, lane);
            stage_tile_n<4>(Bg, 1024, ks * 64, Xs, w, lane);
            __syncthreads();
            #pragma unroll
            for (int kh = 0; kh < 2; ++kh) {
                bf16x8 av[2], bvv[4];
                #pragma unroll
                for (int fm = 0; fm < 2; ++fm) av[fm]  = frag_ld(Ws, wm + fm * 16 + i16, kh * 4 + g);
                #pragma unroll
                for (int fp = 0; fp < 4; ++fp) bvv[fp] = frag_ld(Xs, wp + fp * 16 + i16, kh * 4 + g);
                #pragma unroll
                for (int fm = 0; fm < 2; ++fm)
                    #pragma unroll
                    for (int fp = 0; fp < 4; ++fp)
                        acc[fm][fp] = __builtin_amdgcn_mfma_f32_16x16x32_bf16(av[fm], bvv[fp],
                                                                              acc[fm][fp], 0, 0, 0);
            }
            __syncthreads();
        }
        if (m0 < 256) {
            #pragma unroll
            for (int fp = 0; fp < 4; ++fp) {
                const int pp = pp0 + wp + fp * 16 + i16;
                #pragma unroll
                for (int fm = 0; fm < 2; ++fm) {
                    const int m = m0 + wm + fm * 16 + 4 * g;
                    ushort4 v;
                    v.x = f2bf(acc[fm][fp][0]); v.y = f2bf(acc[fm][fp][1]);
                    v.z = f2bf(acc[fm][fp][2]); v.w = f2bf(acc[fm][fp][3]);
                    *(ushort4*)&kTb[((size_t)bb * 1024 + pp) * 256 + m] = v;
                }
            }
        } else {
            // transpose 64(m) x 128(pp) through LDS, then coalesced rows out
            ushort (*T)[128] = (ushort(*)[128])lds;
            #pragma unroll
            for (int fm = 0; fm < 2; ++fm)
                #pragma unroll
                for (int fp = 0; fp < 4; ++fp)
                    #pragma unroll
                    for (int r = 0; r < 4; ++r)
                        T[wm + fm * 16 + 4 * g + r][wp + fp * 16 + i16] = f2bf(acc[fm][fp][r]);
            __syncthreads();
            #pragma unroll
            for (int u = 0; u < 4; ++u) {
                const int chunk = u * 256 + tid;
                const int row = chunk >> 4, slot = chunk & 15;
                const int mg = m0 - 256 + row;
                const int hh = mg >> 5, cc = mg & 31;
                const uint4 val = *(uint4*)&T[row][slot * 8];
                *(uint4*)&vTtb[((size_t)(bb * 8 + hh) * 32 + cc) * 1024 + pp0 + slot * 8] = val;
            }
        }
    }
}

// ---------------------------------------------------------------------------
// out_mfma: out[b][o][p] = sum_c Wout[o][c]*(sumT[b][p][c]+obT[b][p][c]).
// ---------------------------------------------------------------------------
__global__ __launch_bounds__(256) void out_mfma(
    const float* __restrict__ sumT, const ushort* __restrict__ obT,
    const ushort* __restrict__ Woutb, float* __restrict__ out)
{
    __shared__ __align__(16) ushort lds[16384];
    ushort* Ss = lds; ushort* Wo = lds + 8192;
    const int tid = threadIdx.x, lane = tid & 63, w = tid >> 6;
    const int g = lane >> 4, i16 = lane & 15;
    const int p0 = blockIdx.x * 128, o0 = blockIdx.y * 128, bb = blockIdx.z;
    const int wpp = (w >> 1) * 64, wo = (w & 1) * 64;
    const float* Sg = sumT + ((size_t)bb * 4096 + p0) * 256;
    const ushort* Og = obT + ((size_t)bb * 4096 + p0) * 256;
    const ushort* Bgw = Woutb + (size_t)o0 * 256;
    const int srow = tid >> 1, shalf = tid & 1;
    f32x4 acc[4][4] = {};
    for (int ks = 0; ks < 4; ++ks) {
        {   // reg-stage A: (fp32 sumT + bf16 obT) -> bf16, swizzled ds_write
            const float* src = Sg + (size_t)srow * 256 + ks * 64 + shalf * 32;
            const ushort* osrc = Og + (size_t)srow * 256 + ks * 64 + shalf * 32;
            #pragma unroll
            for (int jj = 0; jj < 4; ++jj) {
                const float4 f0 = *(const float4*)&src[jj * 8];
                const float4 f1 = *(const float4*)&src[jj * 8 + 4];
                const uint2 b0 = *(const uint2*)&osrc[jj * 8];
                const uint2 b1 = *(const uint2*)&osrc[jj * 8 + 4];
                uint4 pk;
                pk.x = pk2(f0.x + bf2f(b0.x & 0xffffu), f0.y + bf2f(b0.x >> 16));
                pk.y = pk2(f0.z + bf2f(b0.y & 0xffffu), f0.w + bf2f(b0.y >> 16));
                pk.z = pk2(f1.x + bf2f(b1.x & 0xffffu), f1.y + bf2f(b1.x >> 16));
                pk.w = pk2(f1.z + bf2f(b1.y & 0xffffu), f1.w + bf2f(b1.y >> 16));
                const int slog = shalf * 4 + jj;
                const int sp = slog ^ (srow & 7);
                *(uint4*)&Ss[(size_t)srow * 64 + sp * 8] = pk;
            }
        }
        stage_tile(Bgw, 256, ks * 64, Wo, w, lane);
        __syncthreads();
        MFMA_STEP(Ss, Wo, wpp, wo);
        __syncthreads();
    }
    #pragma unroll
    for (int fo = 0; fo < 4; ++fo) {
        const int o = o0 + wo + fo * 16 + i16;
        #pragma unroll
        for (int fp = 0; fp < 4; ++fp) {
            const int p = p0 + wpp + fp * 16 + 4 * g;
            const float4 v = make_float4(acc[fp][fo][0], acc[fp][fo][1],
                                         acc[fp][fo][2], acc[fp][fo][3]);
            *(float4*)&out[(size_t)bb * 1048576 + (size_t)o * 4096 + p] = v;
        }
    }
}

// ---------------------------------------------------------------------------
// attn_fused: T1 XCD-aware swizzle (bid = (orig&7)*192 + orig>>3; bijective,
// 1536 = 8*192): each XCD gets 192 consecutive logical blocks = 6 full (b,h)
// groups, so each 128KB K/V slab lives in exactly one XCD's L2 and is reused
// 32x. Blocks [0,1024) = attn_img (R4-exact); [1024,1536) = attn_batch.
// ---------------------------------------------------------------------------
__global__ __launch_bounds__(256) void attn_fused(
    const ushort* __restrict__ qTb, const ushort* __restrict__ kTb,
    const ushort* __restrict__ vTtb, const ushort* __restrict__ qbT,
    const ushort* __restrict__ kvbT, float* __restrict__ sumT,
    ushort* __restrict__ obT)
{
    __shared__ __align__(16) ushort smem[16704];
    const int orig = blockIdx.x;
    const int bid = (orig & 7) * 192 + (orig >> 3);   // T1 XCD swizzle
    const int tid = threadIdx.x;

    if (bid < 1024) {
        // ================= attn_img branch (R4-exact) =================
        ushort (*Ks)[40]  = (ushort(*)[40])smem;
        ushort (*Vts)[136] = (ushort(*)[136])(smem + 5120);
        const int lane = tid & 63;
        const int wv   = tid >> 6;
        const int q    = lane & 31;
        const int hi   = lane >> 5;
        const int bh   = bid >> 5;
        const int b    = bh >> 3, h = bh & 7;
        const int q0   = (bid & 31) * 128 + wv * 32;

        bf16x8 qf[2];
        #pragma unroll
        for (int mm = 0; mm < 2; ++mm)
            qf[mm] = *(const bf16x8*)(qTb + ((size_t)(b * 4096 + q0 + q) * 256 + h * 32 + mm * 16 + hi * 8));

        f32x16 o = {};
        float mrun = -3.0e38f, lrun = 0.f;

        const ushort* kg = kTb + (size_t)b * 1024 * 256 + h * 32;
        const ushort* vg = vTtb + (size_t)bh * 32 * 1024;

        for (int kv0 = 0; kv0 < 1024; kv0 += 128) {
            __syncthreads();
            #pragma unroll
            for (int u = 0; u < 2; ++u) {
                const int chunk = tid + u * 256;
                const int r = chunk >> 2, q4 = chunk & 3;
                *(uint4*)&Ks[r][q4 * 8] = *(const uint4*)(kg + (size_t)(kv0 + r) * 256 + q4 * 8);
                const int c = chunk >> 4, sseg = chunk & 15;
                *(uint4*)&Vts[c][sseg * 8] = *(const uint4*)(vg + (size_t)c * 1024 + kv0 + sseg * 8);
            }
            __syncthreads();

            f32x16 s[4];
            #pragma unroll
            for (int t = 0; t < 4; ++t) {
                const bf16x8 k0 = *(const bf16x8*)&Ks[t * 32 + q][hi * 8];
                const bf16x8 k1 = *(const bf16x8*)&Ks[t * 32 + q][16 + hi * 8];
                f32x16 acc = {};
                acc = __builtin_amdgcn_mfma_f32_32x32x16_bf16(k0, qf[0], acc, 0, 0, 0);
                acc = __builtin_amdgcn_mfma_f32_32x32x16_bf16(k1, qf[1], acc, 0, 0, 0);
                s[t] = acc;
            }
            float pmax = -3.0e38f;
            #pragma unroll
            for (int t = 0; t < 4; ++t)
                #pragma unroll
                for (int r = 0; r < 16; ++r) pmax = fmaxf(pmax, s[t][r]);
            {
                float a_ = pmax, b_ = pmax;
                asm volatile("v_permlane32_swap_b32 %0, %1" : "+v"(a_), "+v"(b_));
                pmax = fmaxf(a_, b_);
            }
            const float mnew  = fmaxf(mrun, pmax);
            const float alpha = __expf(mrun - mnew);
            mrun = mnew;
            float ls = 0.f;
            #pragma unroll
            for (int t = 0; t < 4; ++t)
                #pragma unroll
                for (int r = 0; r < 16; ++r) {
                    const float p = __expf(s[t][r] - mnew);
                    s[t][r] = p; ls += p;
                }
            {
                float a_ = ls, b_ = ls;
                asm volatile("v_permlane32_swap_b32 %0, %1" : "+v"(a_), "+v"(b_));
                ls = a_ + b_;
            }
            lrun = lrun * alpha + ls;
            #pragma unroll
            for (int r = 0; r < 16; ++r) o[r] *= alpha;

            #pragma unroll
            for (int t = 0; t < 4; ++t) {
                unsigned int W[4][2];
                #pragma unroll
                for (int u = 0; u < 4; ++u) {
                    asm("v_cvt_pk_bf16_f32 %0, %1, %2"
                        : "=v"(W[u][0]) : "v"(s[t][4 * u + 0]), "v"(s[t][4 * u + 1]));
                    asm("v_cvt_pk_bf16_f32 %0, %1, %2"
                        : "=v"(W[u][1]) : "v"(s[t][4 * u + 2]), "v"(s[t][4 * u + 3]));
                }
                #pragma unroll
                for (int mm = 0; mm < 2; ++mm) {
                    unsigned int a0 = W[2 * mm][0], b0 = W[2 * mm + 1][0];
                    unsigned int a1 = W[2 * mm][1], b1 = W[2 * mm + 1][1];
                    asm volatile("v_permlane32_swap_b32 %0, %1" : "+v"(a0), "+v"(b0));
                    asm volatile("v_permlane32_swap_b32 %0, %1" : "+v"(a1), "+v"(b1));
                    unsigned int pw[4] = {a0, a1, b0, b1};
                    const bf16x8 pf = *(const bf16x8*)pw;
                    const bf16x8 vf = *(const bf16x8*)&Vts[q][t * 32 + mm * 16 + hi * 8];
                    o = __builtin_amdgcn_mfma_f32_32x32x16_bf16(vf, pf, o, 0, 0, 0);
                }
            }
        }

        const float inv = 1.f / lrun;
        float* dst = sumT + (size_t)(b * 4096 + q0 + q) * 256 + h * 32 + hi * 4;
        #pragma unroll
        for (int u = 0; u < 4; ++u) {
            const float4 v = make_float4(o[4 * u + 0] * inv, o[4 * u + 1] * inv,
                                         o[4 * u + 2] * inv, o[4 * u + 3] * inv);
            *(float4*)&dst[u * 8] = v;
        }
    } else {
        // ================= attn_batch branch (writes obT, no RMW) ===========
        ushort* kvs = smem;
        const int p0 = (bid - 1024) * 8;

        #pragma unroll
        for (int u = 0; u < 8; ++u) {
            const int c = u * 256 + tid;
            const int p = c >> 8;
            const int r = c & 255;
            const int b2 = r >> 6, seg = r & 63;
            const uint4 val = *(const uint4*)(kvbT + ((size_t)(b2 * 4096 + p0 + p)) * 512 + seg * 8);
            *(uint4*)&kvs[p * 2088 + b2 * 520 + seg * 8] = val;
        }
        __syncthreads();

        const int b1 = tid & 3, h = (tid >> 2) & 7, pl = tid >> 5;
        const int p = p0 + pl;
        const ushort* kvp = kvs + pl * 2088;

        const uint4* q4p = (const uint4*)(qbT + ((size_t)b1 * 4096 + p) * 256 + h * 32);
        float q[32];
        #pragma unroll
        for (int i = 0; i < 4; ++i) {
            const uint4 t = q4p[i];
            q[8 * i + 0] = bf2f(t.x & 0xffffu) * ATTN_SCALE; q[8 * i + 1] = bf2f(t.x >> 16) * ATTN_SCALE;
            q[8 * i + 2] = bf2f(t.y & 0xffffu) * ATTN_SCALE; q[8 * i + 3] = bf2f(t.y >> 16) * ATTN_SCALE;
            q[8 * i + 4] = bf2f(t.z & 0xffffu) * ATTN_SCALE; q[8 * i + 5] = bf2f(t.z >> 16) * ATTN_SCALE;
            q[8 * i + 6] = bf2f(t.w & 0xffffu) * ATTN_SCALE; q[8 * i + 7] = bf2f(t.w >> 16) * ATTN_SCALE;
        }

        float s[4];
        #pragma unroll
        for (int b2 = 0; b2 < 4; ++b2) {
            const uint4* k4 = (const uint4*)(kvp + b2 * 520 + h * 32);
            float d = 0.f;
            #pragma unroll
            for (int i = 0; i < 4; ++i) {
                const uint4 w = k4[i];
                d += q[8 * i + 0] * bf2f(w.x & 0xffffu) + q[8 * i + 1] * bf2f(w.x >> 16);
                d += q[8 * i + 2] * bf2f(w.y & 0xffffu) + q[8 * i + 3] * bf2f(w.y >> 16);
                d += q[8 * i + 4] * bf2f(w.z & 0xffffu) + q[8 * i + 5] * bf2f(w.z >> 16);
                d += q[8 * i + 6] * bf2f(w.w & 0xffffu) + q[8 * i + 7] * bf2f(w.w >> 16);
            }
            s[b2] = d;
        }
        const float mx = fmaxf(fmaxf(s[0], s[1]), fmaxf(s[2], s[3]));
        float w[4];
        float lsum = 0.f;
        #pragma unroll
        for (int b2 = 0; b2 < 4; ++b2) { w[b2] = __expf(s[b2] - mx); lsum += w[b2]; }
        const float inv = 1.f / lsum;
        #pragma unroll
        for (int b2 = 0; b2 < 4; ++b2) w[b2] *= inv;

        float acc[32] = {};
        #pragma unroll
        for (int b2 = 0; b2 < 4; ++b2) {
            const uint4* v4 = (const uint4*)(kvp + b2 * 520 + 256 + h * 32);
            const float wb = w[b2];
            #pragma unroll
            for (int i = 0; i < 4; ++i) {
                const uint4 vv = v4[i];
                acc[8 * i + 0] += wb * bf2f(vv.x & 0xffffu); acc[8 * i + 1] += wb * bf2f(vv.x >> 16);
                acc[8 * i + 2] += wb * bf2f(vv.y & 0xffffu); acc[8 * i + 3] += wb * bf2f(vv.y >> 16);
                acc[8 * i + 4] += wb * bf2f(vv.z & 0xffffu); acc[8 * i + 5] += wb * bf2f(vv.z >> 16);
                acc[8 * i + 6] += wb * bf2f(vv.w & 0xffffu); acc[8 * i + 7] += wb * bf2f(vv.w >> 16);
            }
        }
        uint4* o4 = (uint4*)(obT + ((size_t)b1 * 4096 + p) * 256 + h * 32);
        #pragma unroll
        for (int i = 0; i < 4; ++i) {
            uint4 r;
            r.x = pk2(acc[8 * i + 0], acc[8 * i + 1]);
            r.y = pk2(acc[8 * i + 2], acc[8 * i + 3]);
            r.z = pk2(acc[8 * i + 4], acc[8 * i + 5]);
            r.w = pk2(acc[8 * i + 6], acc[8 * i + 7]);
            o4[i] = r;
        }
    }
}

// ---------------------------------------------------------------------------
extern "C" void kernel_launch(void* const* d_in, const int* in_sizes, int n_in,
                              void* d_out, int out_size, void* d_ws, size_t ws_size,
                              hipStream_t stream)
{
    const float* x    = (const float*)d_in[0];
    const float* Wq   = (const float*)d_in[1];
    const float* Wkv  = (const float*)d_in[2];
    const float* Wqb  = (const float*)d_in[3];
    const float* Wkvb = (const float*)d_in[4];
    const float* Wout = (const float*)d_in[5];
    float* out = (float*)d_out;

    // workspace (ushort units). sumT (fp32, 16.78MB) aliases xbfT+xcol.
    // obT (bf16, 8.4MB) appended: total 56.2 MB.
    ushort* base  = (ushort*)d_ws;
    ushort* xbfT  = base;                    // 4,194,304
    ushort* xcol  = base + 4194304;          // 4,194,304
    ushort* Wallb = base + 8388608;          //   262,144
    ushort* Wkvbb = base + 8650752;          //   524,288
    float*  sumT  = (float*)base;            // aliases [0, 8388608) ushorts
    ushort* qTb   = base + 9175040;          // 4,194,304
    ushort* kvbT  = base + 13369344;         // 8,388,608
    ushort* kTb   = base + 21757952;         // 1,048,576
    ushort* vTtb  = base + 22806528;         // 1,048,576
    ushort* Woutb = base + 23855104;         //    65,536
    ushort* obT   = base + 23920640;         // 4,194,304 (bf16 batch-branch out)
    ushort* qbT   = (ushort*)out;            // d_out reused as qb scratch (bf16)

    cvt_fused<<<dim3(1344), 256, 0, stream>>>(x, Wq, Wqb, Wkvb, Wkv, Wout,
                                              xbfT, xcol, Wallb, Wkvbb, Woutb);
    projconv_fused<<<dim3(1280), 256, 0, stream>>>(Wallb, xbfT, Wkvbb, xcol,
                                                   qTb, qbT, kvbT, kTb, vTtb);
    attn_fused<<<dim3(1536), 256, 0, stream>>>(qTb, kTb, vTtb, qbT, kvbT, sumT, obT);
    out_mfma<<<dim3(32, 2, 4), 256, 0, stream>>>(sumT, obT, Woutb, out);
}

// Round 23
// 125.668 us; speedup vs baseline: 1.0022x; 1.0022x over previous
//
#include <hip/hip_runtime.h>

#define ATTN_SCALE 0.17677669529663687f  // 32^-0.5

typedef __attribute__((ext_vector_type(8))) short bf16x8;
typedef __attribute__((ext_vector_type(4))) float f32x4;
typedef __attribute__((ext_vector_type(16))) float f32x16;

__device__ inline unsigned short f2bf(float x) {
    unsigned int u = __float_as_uint(x);
    unsigned int r = u + 0x7fffu + ((u >> 16) & 1u);
    return (unsigned short)(r >> 16);
}
__device__ inline unsigned int pk2(float lo, float hi) {
    return (unsigned int)f2bf(lo) | ((unsigned int)f2bf(hi) << 16);
}
__device__ inline float bf2f(unsigned int u) { return __uint_as_float(u << 16); }

// async 16B global->LDS (lds dest = wave-uniform base + lane*16)
#define GLDS16(gp, lp) \
    __builtin_amdgcn_global_load_lds((const __attribute__((address_space(1))) void*)(gp), \
                                     (__attribute__((address_space(3))) void*)(lp), 16, 0, 0)

// Stage a (NIT*8 rows per wave) x 64col bf16 tile into LDS (row-major, 64/row),
// XOR slot-swizzled via pre-swizzled GLOBAL address (m173 pattern).
template<int NIT>
__device__ inline void stage_tile_n(const ushort* __restrict__ g, int rstride, int kofs,
                                    ushort* lbase, int w, int lane) {
    const int r0 = w * (NIT * 8);
    #pragma unroll
    for (int u = 0; u < NIT; ++u) {
        const int row  = r0 + u * 8 + (lane >> 3);
        const int slog = (lane & 7) ^ (row & 7);
        GLDS16(g + (size_t)row * rstride + kofs + slog * 8,
               lbase + (size_t)(r0 + u * 8) * 64);
    }
}
__device__ inline void stage_tile(const ushort* __restrict__ g, int rstride, int kofs,
                                  ushort* lbase, int w, int lane) {
    stage_tile_n<4>(g, rstride, kofs, lbase, w, lane);
}

// read one 16B MFMA fragment (8 bf16, k-contig) honoring the swizzle
__device__ inline bf16x8 frag_ld(const ushort* t, int row, int slog) {
    return *(const bf16x8*)(t + row * 64 + ((slog ^ (row & 7)) * 8));
}

// one BK=64 MFMA step: 4x4 16x16 frags per wave, acc[fm][fp]
#define MFMA_STEP(WS_, XS_, WM_, WP_)                                                       \
    _Pragma("unroll")                                                                       \
    for (int kh = 0; kh < 2; ++kh) {                                                        \
        bf16x8 av[4], bvv[4];                                                               \
        _Pragma("unroll")                                                                   \
        for (int fm = 0; fm < 4; ++fm) av[fm]  = frag_ld(WS_, WM_ + fm * 16 + i16, kh * 4 + g); \
        _Pragma("unroll")                                                                   \
        for (int fp = 0; fp < 4; ++fp) bvv[fp] = frag_ld(XS_, WP_ + fp * 16 + i16, kh * 4 + g); \
        _Pragma("unroll")                                                                   \
        for (int fm = 0; fm < 4; ++fm)                                                      \
            _Pragma("unroll")                                                               \
            for (int fp = 0; fp < 4; ++fp)                                                  \
                acc[fm][fp] = __builtin_amdgcn_mfma_f32_16x16x32_bf16(av[fm], bvv[fp],      \
                                                                      acc[fm][fp], 0, 0, 0); \
    }

// ---------------------------------------------------------------------------
// cvt_fused: blocks [0,512) = cvt_x (xbfT + xcol); blocks [512,1344) = cvt_w.
// ---------------------------------------------------------------------------
__global__ __launch_bounds__(256) void cvt_fused(
    const float* __restrict__ x,
    const float* __restrict__ Wq, const float* __restrict__ Wqb,
    const float* __restrict__ Wkvb, const float* __restrict__ Wkv,
    const float* __restrict__ Wout,
    ushort* __restrict__ xbfT, ushort* __restrict__ xcol,
    ushort* __restrict__ Wallb, ushort* __restrict__ Wkvbb, ushort* __restrict__ Woutb)
{
    __shared__ float T[128][65];     // [p-local][c] (cvt_x branch only)
    const int bid = blockIdx.x;
    const int t = threadIdx.x;

    if (bid < 512) {
        // ---------------- cvt_x branch ----------------
        const int i2 = bid & 31;
        const int c0 = ((bid >> 5) & 3) * 64;
        const int bb = bid >> 7;
        const int p0 = i2 * 128;
        const float* xb = x + ((size_t)bb * 256 + c0) * 4096 + p0;

        {   // load 64 channels x 128 pixels, transpose into T[p][c]
            const int cc = t >> 2;
            const int pq = (t & 3) * 32;
            #pragma unroll
            for (int u = 0; u < 8; ++u) {
                const float4 v = *(const float4*)&xb[(size_t)cc * 4096 + pq + u * 4];
                T[pq + u * 4 + 0][cc] = v.x; T[pq + u * 4 + 1][cc] = v.y;
                T[pq + u * 4 + 2][cc] = v.z; T[pq + u * 4 + 3][cc] = v.w;
            }
        }
        __syncthreads();

        {   // emit xbfT
            const int pp = t >> 1, ch = (t & 1) * 32;
            const float* row = &T[pp][ch];
            unsigned int pkv[16];
            #pragma unroll
            for (int u = 0; u < 16; ++u) pkv[u] = pk2(row[2 * u], row[2 * u + 1]);
            ushort* dst = xbfT + ((size_t)bb * 4096 + p0 + pp) * 256 + c0 + ch;
            *(uint4*)&dst[0]  = *(uint4*)&pkv[0];
            *(uint4*)&dst[8]  = *(uint4*)&pkv[4];
            *(uint4*)&dst[16] = *(uint4*)&pkv[8];
            *(uint4*)&dst[24] = *(uint4*)&pkv[12];
        }
        {   // emit xcol
            const int j = t >> 3, c8 = (t & 7) * 8;
            unsigned int pkv[16];
            #pragma unroll
            for (int c = 0; c < 8; ++c) {
                pkv[2 * c]     = pk2(T[2 * j][c8 + c],      T[2 * j + 1][c8 + c]);
                pkv[2 * c + 1] = pk2(T[64 + 2 * j][c8 + c], T[65 + 2 * j][c8 + c]);
            }
            ushort* dst = xcol + ((size_t)bb * 1024 + i2 * 32 + j) * 1024 + (size_t)(c0 + c8) * 4;
            *(uint4*)&dst[0]  = *(uint4*)&pkv[0];
            *(uint4*)&dst[8]  = *(uint4*)&pkv[4];
            *(uint4*)&dst[16] = *(uint4*)&pkv[8];
            *(uint4*)&dst[24] = *(uint4*)&pkv[12];
        }
    } else {
        // ---------------- cvt_w branch ----------------
        const int id = (bid - 512) * 256 + t;   // float4-chunk id
        const float* src; ushort* dst;
        if (id < 65536) {
            const int m = id >> 6, c4 = (id & 63) * 4;
            src = (m < 256) ? &Wq[(size_t)m * 256 + c4]
                : (m < 512) ? &Wqb[(size_t)(m - 256) * 256 + c4]
                            : &Wkvb[(size_t)(m - 512) * 256 + c4];
            dst = Wallb + (size_t)id * 4;
        } else if (id < 65536 + 131072) {
            const size_t el = (size_t)(id - 65536) * 4;
            src = &Wkv[el]; dst = Wkvbb + el;
        } else {
            const size_t el = (size_t)(id - 65536 - 131072) * 4;
            src = &Wout[el]; dst = Woutb + el;
        }
        const float4 v = *(const float4*)src;
        ushort4 o; o.x = f2bf(v.x); o.y = f2bf(v.y); o.z = f2bf(v.z); o.w = f2bf(v.w);
        *(ushort4*)dst = o;
    }
}

// ---------------------------------------------------------------------------
// projconv_fused: blocks [0,1024) = proj_mfma; [1024,1280) = conv_mfma.
// ---------------------------------------------------------------------------
__global__ __launch_bounds__(256) void projconv_fused(
    const ushort* __restrict__ Wallb, const ushort* __restrict__ xbfT,
    const ushort* __restrict__ Wkvbb, const ushort* __restrict__ xcol,
    ushort* __restrict__ qTb, ushort* __restrict__ qbT, ushort* __restrict__ kvbT,
    ushort* __restrict__ kTb, ushort* __restrict__ vTtb)
{
    __shared__ __align__(16) ushort lds[16384];
    const int bid = blockIdx.x;
    const int tid = threadIdx.x, lane = tid & 63, w = tid >> 6;
    const int g = lane >> 4, i16 = lane & 15;

    if (bid < 1024) {
        // ---------------- proj branch ----------------
        ushort* Ws = lds; ushort* Xs = lds + 8192;
        const int p0 = (bid & 31) * 128, m0 = ((bid >> 5) & 7) * 128, bb = bid >> 8;
        const int wm = (w >> 1) * 64, wp = (w & 1) * 64;
        const ushort* Ag = Wallb + (size_t)m0 * 256;
        const ushort* Bg = xbfT + ((size_t)bb * 4096 + p0) * 256;
        f32x4 acc[4][4] = {};
        for (int ks = 0; ks < 4; ++ks) {
            stage_tile(Ag, 256, ks * 64, Ws, w, lane);
            stage_tile(Bg, 256, ks * 64, Xs, w, lane);
            __syncthreads();
            MFMA_STEP(Ws, Xs, wm, wp);
            __syncthreads();
        }
        #pragma unroll
        for (int fp = 0; fp < 4; ++fp) {
            const int p = p0 + wp + fp * 16 + i16;
            #pragma unroll
            for (int fm = 0; fm < 4; ++fm) {
                const int m = m0 + wm + fm * 16 + 4 * g;
                if (m0 < 256) {
                    ushort4 v;
                    v.x = f2bf(acc[fm][fp][0] * ATTN_SCALE); v.y = f2bf(acc[fm][fp][1] * ATTN_SCALE);
                    v.z = f2bf(acc[fm][fp][2] * ATTN_SCALE); v.w = f2bf(acc[fm][fp][3] * ATTN_SCALE);
                    *(ushort4*)&qTb[((size_t)bb * 4096 + p) * 256 + m] = v;
                } else if (m0 < 512) {
                    ushort4 v;
                    v.x = f2bf(acc[fm][fp][0]); v.y = f2bf(acc[fm][fp][1]);
                    v.z = f2bf(acc[fm][fp][2]); v.w = f2bf(acc[fm][fp][3]);
                    *(ushort4*)&qbT[((size_t)bb * 4096 + p) * 256 + (m - 256)] = v;
                } else {
                    ushort4 v;
                    v.x = f2bf(acc[fm][fp][0]); v.y = f2bf(acc[fm][fp][1]);
                    v.z = f2bf(acc[fm][fp][2]); v.w = f2bf(acc[fm][fp][3]);
                    *(ushort4*)&kvbT[((size_t)bb * 4096 + p) * 512 + (m - 512)] = v;
                }
            }
        }
    } else {
        // ---------------- conv branch ----------------
        ushort* Ws = lds;          // 64 rows x 64
        ushort* Xs = lds + 4096;   // 128 rows x 64
        const int id = bid - 1024;
        const int pp0 = (id & 7) * 128, m0 = ((id >> 3) & 7) * 64, bb = id >> 6;
        const int wm = (w >> 1) * 32, wp = (w & 1) * 64;
        const ushort* Ag = Wkvbb + (size_t)m0 * 1024;
        const ushort* Bg = xcol + ((size_t)bb * 1024 + pp0) * 1024;
        f32x4 acc[2][4] = {};
        for (int ks = 0; ks < 16; ++ks) {
            stage_tile_n<2>(Ag, 1024, ks * 64, Ws, w, lane);
            stage_tile_n<4>(Bg, 1024, ks * 64, Xs, w, lane);
            __syncthreads();
            #pragma unroll
            for (int kh = 0; kh < 2; ++kh) {
                bf16x8 av[2], bvv[4];
                #pragma unroll
                for (int fm = 0; fm < 2; ++fm) av[fm]  = frag_ld(Ws, wm + fm * 16 + i16, kh * 4 + g);
                #pragma unroll
                for (int fp = 0; fp < 4; ++fp) bvv[fp] = frag_ld(Xs, wp + fp * 16 + i16, kh * 4 + g);
                #pragma unroll
                for (int fm = 0; fm < 2; ++fm)
                    #pragma unroll
                    for (int fp = 0; fp < 4; ++fp)
                        acc[fm][fp] = __builtin_amdgcn_mfma_f32_16x16x32_bf16(av[fm], bvv[fp],
                                                                              acc[fm][fp], 0, 0, 0);
            }
            __syncthreads();
        }
        if (m0 < 256) {
            #pragma unroll
            for (int fp = 0; fp < 4; ++fp) {
                const int pp = pp0 + wp + fp * 16 + i16;
                #pragma unroll
                for (int fm = 0; fm < 2; ++fm) {
                    const int m = m0 + wm + fm * 16 + 4 * g;
                    ushort4 v;
                    v.x = f2bf(acc[fm][fp][0]); v.y = f2bf(acc[fm][fp][1]);
                    v.z = f2bf(acc[fm][fp][2]); v.w = f2bf(acc[fm][fp][3]);
                    *(ushort4*)&kTb[((size_t)bb * 1024 + pp) * 256 + m] = v;
                }
            }
        } else {
            // transpose 64(m) x 128(pp) through LDS, then coalesced rows out
            ushort (*T)[128] = (ushort(*)[128])lds;
            #pragma unroll
            for (int fm = 0; fm < 2; ++fm)
                #pragma unroll
                for (int fp = 0; fp < 4; ++fp)
                    #pragma unroll
                    for (int r = 0; r < 4; ++r)
                        T[wm + fm * 16 + 4 * g + r][wp + fp * 16 + i16] = f2bf(acc[fm][fp][r]);
            __syncthreads();
            #pragma unroll
            for (int u = 0; u < 4; ++u) {
                const int chunk = u * 256 + tid;
                const int row = chunk >> 4, slot = chunk & 15;
                const int mg = m0 - 256 + row;
                const int hh = mg >> 5, cc = mg & 31;
                const uint4 val = *(uint4*)&T[row][slot * 8];
                *(uint4*)&vTtb[((size_t)(bb * 8 + hh) * 32 + cc) * 1024 + pp0 + slot * 8] = val;
            }
        }
    }
}

// ---------------------------------------------------------------------------
// out_mfma: out[b][o][p] = sum_c Wout[o][c]*(sumT[b][p][c]+obT[b][p][c]).
// ---------------------------------------------------------------------------
__global__ __launch_bounds__(256) void out_mfma(
    const float* __restrict__ sumT, const ushort* __restrict__ obT,
    const ushort* __restrict__ Woutb, float* __restrict__ out)
{
    __shared__ __align__(16) ushort lds[16384];
    ushort* Ss = lds; ushort* Wo = lds + 8192;
    const int tid = threadIdx.x, lane = tid & 63, w = tid >> 6;
    const int g = lane >> 4, i16 = lane & 15;
    const int p0 = blockIdx.x * 128, o0 = blockIdx.y * 128, bb = blockIdx.z;
    const int wpp = (w >> 1) * 64, wo = (w & 1) * 64;
    const float* Sg = sumT + ((size_t)bb * 4096 + p0) * 256;
    const ushort* Og = obT + ((size_t)bb * 4096 + p0) * 256;
    const ushort* Bgw = Woutb + (size_t)o0 * 256;
    const int srow = tid >> 1, shalf = tid & 1;
    f32x4 acc[4][4] = {};
    for (int ks = 0; ks < 4; ++ks) {
        {   // reg-stage A: (fp32 sumT + bf16 obT) -> bf16, swizzled ds_write
            const float* src = Sg + (size_t)srow * 256 + ks * 64 + shalf * 32;
            const ushort* osrc = Og + (size_t)srow * 256 + ks * 64 + shalf * 32;
            #pragma unroll
            for (int jj = 0; jj < 4; ++jj) {
                const float4 f0 = *(const float4*)&src[jj * 8];
                const float4 f1 = *(const float4*)&src[jj * 8 + 4];
                const uint2 b0 = *(const uint2*)&osrc[jj * 8];
                const uint2 b1 = *(const uint2*)&osrc[jj * 8 + 4];
                uint4 pk;
                pk.x = pk2(f0.x + bf2f(b0.x & 0xffffu), f0.y + bf2f(b0.x >> 16));
                pk.y = pk2(f0.z + bf2f(b0.y & 0xffffu), f0.w + bf2f(b0.y >> 16));
                pk.z = pk2(f1.x + bf2f(b1.x & 0xffffu), f1.y + bf2f(b1.x >> 16));
                pk.w = pk2(f1.z + bf2f(b1.y & 0xffffu), f1.w + bf2f(b1.y >> 16));
                const int slog = shalf * 4 + jj;
                const int sp = slog ^ (srow & 7);
                *(uint4*)&Ss[(size_t)srow * 64 + sp * 8] = pk;
            }
        }
        stage_tile(Bgw, 256, ks * 64, Wo, w, lane);
        __syncthreads();
        MFMA_STEP(Ss, Wo, wpp, wo);
        __syncthreads();
    }
    #pragma unroll
    for (int fo = 0; fo < 4; ++fo) {
        const int o = o0 + wo + fo * 16 + i16;
        #pragma unroll
        for (int fp = 0; fp < 4; ++fp) {
            const int p = p0 + wpp + fp * 16 + 4 * g;
            const float4 v = make_float4(acc[fp][fo][0], acc[fp][fo][1],
                                         acc[fp][fo][2], acc[fp][fo][3]);
            *(float4*)&out[(size_t)bb * 1048576 + (size_t)o * 4096 + p] = v;
        }
    }
}

// ---------------------------------------------------------------------------
// attn_fused: T1 XCD-aware swizzle (bid = (orig&7)*192 + orig>>3; bijective,
// 1536 = 8*192): each XCD gets 192 consecutive logical blocks = 6 full (b,h)
// groups, so each 128KB K/V slab lives in exactly one XCD's L2 and is reused
// 32x. Blocks [0,1024) = attn_img (R4-exact); [1024,1536) = attn_batch.
// ---------------------------------------------------------------------------
__global__ __launch_bounds__(256) void attn_fused(
    const ushort* __restrict__ qTb, const ushort* __restrict__ kTb,
    const ushort* __restrict__ vTtb, const ushort* __restrict__ qbT,
    const ushort* __restrict__ kvbT, float* __restrict__ sumT,
    ushort* __restrict__ obT)
{
    __shared__ __align__(16) ushort smem[16704];
    const int orig = blockIdx.x;
    const int bid = (orig & 7) * 192 + (orig >> 3);   // T1 XCD swizzle
    const int tid = threadIdx.x;

    if (bid < 1024) {
        // ================= attn_img branch (R4-exact) =================
        ushort (*Ks)[40]  = (ushort(*)[40])smem;
        ushort (*Vts)[136] = (ushort(*)[136])(smem + 5120);
        const int lane = tid & 63;
        const int wv   = tid >> 6;
        const int q    = lane & 31;
        const int hi   = lane >> 5;
        const int bh   = bid >> 5;
        const int b    = bh >> 3, h = bh & 7;
        const int q0   = (bid & 31) * 128 + wv * 32;

        bf16x8 qf[2];
        #pragma unroll
        for (int mm = 0; mm < 2; ++mm)
            qf[mm] = *(const bf16x8*)(qTb + ((size_t)(b * 4096 + q0 + q) * 256 + h * 32 + mm * 16 + hi * 8));

        f32x16 o = {};
        float mrun = -3.0e38f, lrun = 0.f;

        const ushort* kg = kTb + (size_t)b * 1024 * 256 + h * 32;
        const ushort* vg = vTtb + (size_t)bh * 32 * 1024;

        for (int kv0 = 0; kv0 < 1024; kv0 += 128) {
            __syncthreads();
            #pragma unroll
            for (int u = 0; u < 2; ++u) {
                const int chunk = tid + u * 256;
                const int r = chunk >> 2, q4 = chunk & 3;
                *(uint4*)&Ks[r][q4 * 8] = *(const uint4*)(kg + (size_t)(kv0 + r) * 256 + q4 * 8);
                const int c = chunk >> 4, sseg = chunk & 15;
                *(uint4*)&Vts[c][sseg * 8] = *(const uint4*)(vg + (size_t)c * 1024 + kv0 + sseg * 8);
            }
            __syncthreads();

            f32x16 s[4];
            #pragma unroll
            for (int t = 0; t < 4; ++t) {
                const bf16x8 k0 = *(const bf16x8*)&Ks[t * 32 + q][hi * 8];
                const bf16x8 k1 = *(const bf16x8*)&Ks[t * 32 + q][16 + hi * 8];
                f32x16 acc = {};
                acc = __builtin_amdgcn_mfma_f32_32x32x16_bf16(k0, qf[0], acc, 0, 0, 0);
                acc = __builtin_amdgcn_mfma_f32_32x32x16_bf16(k1, qf[1], acc, 0, 0, 0);
                s[t] = acc;
            }
            float pmax = -3.0e38f;
            #pragma unroll
            for (int t = 0; t < 4; ++t)
                #pragma unroll
                for (int r = 0; r < 16; ++r) pmax = fmaxf(pmax, s[t][r]);
            {
                float a_ = pmax, b_ = pmax;
                asm volatile("v_permlane32_swap_b32 %0, %1" : "+v"(a_), "+v"(b_));
                pmax = fmaxf(a_, b_);
            }
            const float mnew  = fmaxf(mrun, pmax);
            const float alpha = __expf(mrun - mnew);
            mrun = mnew;
            float ls = 0.f;
            #pragma unroll
            for (int t = 0; t < 4; ++t)
                #pragma unroll
                for (int r = 0; r < 16; ++r) {
                    const float p = __expf(s[t][r] - mnew);
                    s[t][r] = p; ls += p;
                }
            {
                float a_ = ls, b_ = ls;
                asm volatile("v_permlane32_swap_b32 %0, %1" : "+v"(a_), "+v"(b_));
                ls = a_ + b_;
            }
            lrun = lrun * alpha + ls;
            #pragma unroll
            for (int r = 0; r < 16; ++r) o[r] *= alpha;

            #pragma unroll
            for (int t = 0; t < 4; ++t) {
                unsigned int W[4][2];
                #pragma unroll
                for (int u = 0; u < 4; ++u) {
                    asm("v_cvt_pk_bf16_f32 %0, %1, %2"
                        : "=v"(W[u][0]) : "v"(s[t][4 * u + 0]), "v"(s[t][4 * u + 1]));
                    asm("v_cvt_pk_bf16_f32 %0, %1, %2"
                        : "=v"(W[u][1]) : "v"(s[t][4 * u + 2]), "v"(s[t][4 * u + 3]));
                }
                #pragma unroll
                for (int mm = 0; mm < 2; ++mm) {
                    unsigned int a0 = W[2 * mm][0], b0 = W[2 * mm + 1][0];
                    unsigned int a1 = W[2 * mm][1], b1 = W[2 * mm + 1][1];
                    asm volatile("v_permlane32_swap_b32 %0, %1" : "+v"(a0), "+v"(b0));
                    asm volatile("v_permlane32_swap_b32 %0, %1" : "+v"(a1), "+v"(b1));
                    unsigned int pw[4] = {a0, a1, b0, b1};
                    const bf16x8 pf = *(const bf16x8*)pw;
                    const bf16x8 vf = *(const bf16x8*)&Vts[q][t * 32 + mm * 16 + hi * 8];
                    o = __builtin_amdgcn_mfma_f32_32x32x16_bf16(vf, pf, o, 0, 0, 0);
                }
            }
        }

        const float inv = 1.f / lrun;
        float* dst = sumT + (size_t)(b * 4096 + q0 + q) * 256 + h * 32 + hi * 4;
        #pragma unroll
        for (int u = 0; u < 4; ++u) {
            const float4 v = make_float4(o[4 * u + 0] * inv, o[4 * u + 1] * inv,
                                         o[4 * u + 2] * inv, o[4 * u + 3] * inv);
            *(float4*)&dst[u * 8] = v;
        }
    } else {
        // ================= attn_batch branch (writes obT, no RMW) ===========
        ushort* kvs = smem;
        const int p0 = (bid - 1024) * 8;

        #pragma unroll
        for (int u = 0; u < 8; ++u) {
            const int c = u * 256 + tid;
            const int p = c >> 8;
            const int r = c & 255;
            const int b2 = r >> 6, seg = r & 63;
            const uint4 val = *(const uint4*)(kvbT + ((size_t)(b2 * 4096 + p0 + p)) * 512 + seg * 8);
            *(uint4*)&kvs[p * 2088 + b2 * 520 + seg * 8] = val;
        }
        __syncthreads();

        const int b1 = tid & 3, h = (tid >> 2) & 7, pl = tid >> 5;
        const int p = p0 + pl;
        const ushort* kvp = kvs + pl * 2088;

        const uint4* q4p = (const uint4*)(qbT + ((size_t)b1 * 4096 + p) * 256 + h * 32);
        float q[32];
        #pragma unroll
        for (int i = 0; i < 4; ++i) {
            const uint4 t = q4p[i];
            q[8 * i + 0] = bf2f(t.x & 0xffffu) * ATTN_SCALE; q[8 * i + 1] = bf2f(t.x >> 16) * ATTN_SCALE;
            q[8 * i + 2] = bf2f(t.y & 0xffffu) * ATTN_SCALE; q[8 * i + 3] = bf2f(t.y >> 16) * ATTN_SCALE;
            q[8 * i + 4] = bf2f(t.z & 0xffffu) * ATTN_SCALE; q[8 * i + 5] = bf2f(t.z >> 16) * ATTN_SCALE;
            q[8 * i + 6] = bf2f(t.w & 0xffffu) * ATTN_SCALE; q[8 * i + 7] = bf2f(t.w >> 16) * ATTN_SCALE;
        }

        float s[4];
        #pragma unroll
        for (int b2 = 0; b2 < 4; ++b2) {
            const uint4* k4 = (const uint4*)(kvp + b2 * 520 + h * 32);
            float d = 0.f;
            #pragma unroll
            for (int i = 0; i < 4; ++i) {
                const uint4 w = k4[i];
                d += q[8 * i + 0] * bf2f(w.x & 0xffffu) + q[8 * i + 1] * bf2f(w.x >> 16);
                d += q[8 * i + 2] * bf2f(w.y & 0xffffu) + q[8 * i + 3] * bf2f(w.y >> 16);
                d += q[8 * i + 4] * bf2f(w.z & 0xffffu) + q[8 * i + 5] * bf2f(w.z >> 16);
                d += q[8 * i + 6] * bf2f(w.w & 0xffffu) + q[8 * i + 7] * bf2f(w.w >> 16);
            }
            s[b2] = d;
        }
        const float mx = fmaxf(fmaxf(s[0], s[1]), fmaxf(s[2], s[3]));
        float w[4];
        float lsum = 0.f;
        #pragma unroll
        for (int b2 = 0; b2 < 4; ++b2) { w[b2] = __expf(s[b2] - mx); lsum += w[b2]; }
        const float inv = 1.f / lsum;
        #pragma unroll
        for (int b2 = 0; b2 < 4; ++b2) w[b2] *= inv;

        float acc[32] = {};
        #pragma unroll
        for (int b2 = 0; b2 < 4; ++b2) {
            const uint4* v4 = (const uint4*)(kvp + b2 * 520 + 256 + h * 32);
            const float wb = w[b2];
            #pragma unroll
            for (int i = 0; i < 4; ++i) {
                const uint4 vv = v4[i];
                acc[8 * i + 0] += wb * bf2f(vv.x & 0xffffu); acc[8 * i + 1] += wb * bf2f(vv.x >> 16);
                acc[8 * i + 2] += wb * bf2f(vv.y & 0xffffu); acc[8 * i + 3] += wb * bf2f(vv.y >> 16);
                acc[8 * i + 4] += wb * bf2f(vv.z & 0xffffu); acc[8 * i + 5] += wb * bf2f(vv.z >> 16);
                acc[8 * i + 6] += wb * bf2f(vv.w & 0xffffu); acc[8 * i + 7] += wb * bf2f(vv.w >> 16);
            }
        }
        uint4* o4 = (uint4*)(obT + ((size_t)b1 * 4096 + p) * 256 + h * 32);
        #pragma unroll
        for (int i = 0; i < 4; ++i) {
            uint4 r;
            r.x = pk2(acc[8 * i + 0], acc[8 * i + 1]);
            r.y = pk2(acc[8 * i + 2], acc[8 * i + 3]);
            r.z = pk2(acc[8 * i + 4], acc[8 * i + 5]);
            r.w = pk2(acc[8 * i + 6], acc[8 * i + 7]);
            o4[i] = r;
        }
    }
}

// ---------------------------------------------------------------------------
extern "C" void kernel_launch(void* const* d_in, const int* in_sizes, int n_in,
                              void* d_out, int out_size, void* d_ws, size_t ws_size,
                              hipStream_t stream)
{
    const float* x    = (const float*)d_in[0];
    const float* Wq   = (const float*)d_in[1];
    const float* Wkv  = (const float*)d_in[2];
    const float* Wqb  = (const float*)d_in[3];
    const float* Wkvb = (const float*)d_in[4];
    const float* Wout = (const float*)d_in[5];
    float* out = (float*)d_out;

    // workspace (ushort units). sumT (fp32, 16.78MB) aliases xbfT+xcol.
    // obT (bf16, 8.4MB) appended: total 56.2 MB.
    ushort* base  = (ushort*)d_ws;
    ushort* xbfT  = base;                    // 4,194,304
    ushort* xcol  = base + 4194304;          // 4,194,304
    ushort* Wallb = base + 8388608;          //   262,144
    ushort* Wkvbb = base + 8650752;          //   524,288
    float*  sumT  = (float*)base;            // aliases [0, 8388608) ushorts
    ushort* qTb   = base + 9175040;          // 4,194,304
    ushort* kvbT  = base + 13369344;         // 8,388,608
    ushort* kTb   = base + 21757952;         // 1,048,576
    ushort* vTtb  = base + 22806528;         // 1,048,576
    ushort* Woutb = base + 23855104;         //    65,536
    ushort* obT   = base + 23920640;         // 4,194,304 (bf16 batch-branch out)
    ushort* qbT   = (ushort*)out;            // d_out reused as qb scratch (bf16)

    cvt_fused<<<dim3(1344), 256, 0, stream>>>(x, Wq, Wqb, Wkvb, Wkv, Wout,
                                              xbfT, xcol, Wallb, Wkvbb, Woutb);
    projconv_fused<<<dim3(1280), 256, 0, stream>>>(Wallb, xbfT, Wkvbb, xcol,
                                                   qTb, qbT, kvbT, kTb, vTtb);
    attn_fused<<<dim3(1536), 256, 0, stream>>>(qTb, kTb, vTtb, qbT, kvbT, sumT, obT);
    out_mfma<<<dim3(32, 2, 4), 256, 0, stream>>>(sumT, obT, Woutb, out);
}

// Round 24
// 107.896 us; speedup vs baseline: 1.1673x; 1.1647x over previous
//
#include <hip/hip_runtime.h>

#define ATTN_SCALE 0.17677669529663687f  // 32^-0.5

typedef __attribute__((ext_vector_type(8))) short bf16x8;
typedef __attribute__((ext_vector_type(4))) float f32x4;
typedef __attribute__((ext_vector_type(16))) float f32x16;

__device__ inline unsigned short f2bf(float x) {
    unsigned int u = __float_as_uint(x);
    unsigned int r = u + 0x7fffu + ((u >> 16) & 1u);
    return (unsigned short)(r >> 16);
}
__device__ inline unsigned int pk2(float lo, float hi) {
    return (unsigned int)f2bf(lo) | ((unsigned int)f2bf(hi) << 16);
}
__device__ inline float bf2f(unsigned int u) { return __uint_as_float(u << 16); }

// async 16B global->LDS (lds dest = wave-uniform base + lane*16)
#define GLDS16(gp, lp) \
    __builtin_amdgcn_global_load_lds((const __attribute__((address_space(1))) void*)(gp), \
                                     (__attribute__((address_space(3))) void*)(lp), 16, 0, 0)

// Stage a (NIT*8 rows per wave) x 64col bf16 tile into LDS (row-major, 64/row),
// XOR slot-swizzled via pre-swizzled GLOBAL address (m173 pattern).
template<int NIT>
__device__ inline void stage_tile_n(const ushort* __restrict__ g, int rstride, int kofs,
                                    ushort* lbase, int w, int lane) {
    const int r0 = w * (NIT * 8);
    #pragma unroll
    for (int u = 0; u < NIT; ++u) {
        const int row  = r0 + u * 8 + (lane >> 3);
        const int slog = (lane & 7) ^ (row & 7);
        GLDS16(g + (size_t)row * rstride + kofs + slog * 8,
               lbase + (size_t)(r0 + u * 8) * 64);
    }
}
__device__ inline void stage_tile(const ushort* __restrict__ g, int rstride, int kofs,
                                  ushort* lbase, int w, int lane) {
    stage_tile_n<4>(g, rstride, kofs, lbase, w, lane);
}

// read one 16B MFMA fragment (8 bf16, k-contig) honoring the swizzle
__device__ inline bf16x8 frag_ld(const ushort* t, int row, int slog) {
    return *(const bf16x8*)(t + row * 64 + ((slog ^ (row & 7)) * 8));
}

// one BK=64 MFMA step: 4x4 16x16 frags per wave, acc[fm][fp]
#define MFMA_STEP(WS_, XS_, WM_, WP_)                                                       \
    _Pragma("unroll")                                                                       \
    for (int kh = 0; kh < 2; ++kh) {                                                        \
        bf16x8 av[4], bvv[4];                                                               \
        _Pragma("unroll")                                                                   \
        for (int fm = 0; fm < 4; ++fm) av[fm]  = frag_ld(WS_, WM_ + fm * 16 + i16, kh * 4 + g); \
        _Pragma("unroll")                                                                   \
        for (int fp = 0; fp < 4; ++fp) bvv[fp] = frag_ld(XS_, WP_ + fp * 16 + i16, kh * 4 + g); \
        _Pragma("unroll")                                                                   \
        for (int fm = 0; fm < 4; ++fm)                                                      \
            _Pragma("unroll")                                                               \
            for (int fp = 0; fp < 4; ++fp)                                                  \
                acc[fm][fp] = __builtin_amdgcn_mfma_f32_16x16x32_bf16(av[fm], bvv[fp],      \
                                                                      acc[fm][fp], 0, 0, 0); \
    }

// ---------------------------------------------------------------------------
// cvt_fused: blocks [0,512) = cvt_x (xbfT + xcol); blocks [512,1344) = cvt_w.
// ---------------------------------------------------------------------------
__global__ __launch_bounds__(256) void cvt_fused(
    const float* __restrict__ x,
    const float* __restrict__ Wq, const float* __restrict__ Wqb,
    const float* __restrict__ Wkvb, const float* __restrict__ Wkv,
    const float* __restrict__ Wout,
    ushort* __restrict__ xbfT, ushort* __restrict__ xcol,
    ushort* __restrict__ Wallb, ushort* __restrict__ Wkvbb, ushort* __restrict__ Woutb)
{
    __shared__ float T[128][65];     // [p-local][c] (cvt_x branch only)
    const int bid = blockIdx.x;
    const int t = threadIdx.x;

    if (bid < 512) {
        // ---------------- cvt_x branch ----------------
        const int i2 = bid & 31;
        const int c0 = ((bid >> 5) & 3) * 64;
        const int bb = bid >> 7;
        const int p0 = i2 * 128;
        const float* xb = x + ((size_t)bb * 256 + c0) * 4096 + p0;

        {   // load 64 channels x 128 pixels, transpose into T[p][c]
            const int cc = t >> 2;
            const int pq = (t & 3) * 32;
            #pragma unroll
            for (int u = 0; u < 8; ++u) {
                const float4 v = *(const float4*)&xb[(size_t)cc * 4096 + pq + u * 4];
                T[pq + u * 4 + 0][cc] = v.x; T[pq + u * 4 + 1][cc] = v.y;
                T[pq + u * 4 + 2][cc] = v.z; T[pq + u * 4 + 3][cc] = v.w;
            }
        }
        __syncthreads();

        {   // emit xbfT
            const int pp = t >> 1, ch = (t & 1) * 32;
            const float* row = &T[pp][ch];
            unsigned int pkv[16];
            #pragma unroll
            for (int u = 0; u < 16; ++u) pkv[u] = pk2(row[2 * u], row[2 * u + 1]);
            ushort* dst = xbfT + ((size_t)bb * 4096 + p0 + pp) * 256 + c0 + ch;
            *(uint4*)&dst[0]  = *(uint4*)&pkv[0];
            *(uint4*)&dst[8]  = *(uint4*)&pkv[4];
            *(uint4*)&dst[16] = *(uint4*)&pkv[8];
            *(uint4*)&dst[24] = *(uint4*)&pkv[12];
        }
        {   // emit xcol
            const int j = t >> 3, c8 = (t & 7) * 8;
            unsigned int pkv[16];
            #pragma unroll
            for (int c = 0; c < 8; ++c) {
                pkv[2 * c]     = pk2(T[2 * j][c8 + c],      T[2 * j + 1][c8 + c]);
                pkv[2 * c + 1] = pk2(T[64 + 2 * j][c8 + c], T[65 + 2 * j][c8 + c]);
            }
            ushort* dst = xcol + ((size_t)bb * 1024 + i2 * 32 + j) * 1024 + (size_t)(c0 + c8) * 4;
            *(uint4*)&dst[0]  = *(uint4*)&pkv[0];
            *(uint4*)&dst[8]  = *(uint4*)&pkv[4];
            *(uint4*)&dst[16] = *(uint4*)&pkv[8];
            *(uint4*)&dst[24] = *(uint4*)&pkv[12];
        }
    } else {
        // ---------------- cvt_w branch ----------------
        const int id = (bid - 512) * 256 + t;   // float4-chunk id
        const float* src; ushort* dst;
        if (id < 65536) {
            const int m = id >> 6, c4 = (id & 63) * 4;
            src = (m < 256) ? &Wq[(size_t)m * 256 + c4]
                : (m < 512) ? &Wqb[(size_t)(m - 256) * 256 + c4]
                            : &Wkvb[(size_t)(m - 512) * 256 + c4];
            dst = Wallb + (size_t)id * 4;
        } else if (id < 65536 + 131072) {
            const size_t el = (size_t)(id - 65536) * 4;
            src = &Wkv[el]; dst = Wkvbb + el;
        } else {
            const size_t el = (size_t)(id - 65536 - 131072) * 4;
            src = &Wout[el]; dst = Woutb + el;
        }
        const float4 v = *(const float4*)src;
        ushort4 o; o.x = f2bf(v.x); o.y = f2bf(v.y); o.z = f2bf(v.z); o.w = f2bf(v.w);
        *(ushort4*)dst = o;
    }
}

// ---------------------------------------------------------------------------
// projconv_fused: blocks [0,1024) = proj_mfma; [1024,1280) = conv_mfma.
// ---------------------------------------------------------------------------
__global__ __launch_bounds__(256) void projconv_fused(
    const ushort* __restrict__ Wallb, const ushort* __restrict__ xbfT,
    const ushort* __restrict__ Wkvbb, const ushort* __restrict__ xcol,
    ushort* __restrict__ qTb, ushort* __restrict__ qbT, ushort* __restrict__ kvbT,
    ushort* __restrict__ kTb, ushort* __restrict__ vTtb)
{
    __shared__ __align__(16) ushort lds[16384];
    const int bid = blockIdx.x;
    const int tid = threadIdx.x, lane = tid & 63, w = tid >> 6;
    const int g = lane >> 4, i16 = lane & 15;

    if (bid < 1024) {
        // ---------------- proj branch ----------------
        ushort* Ws = lds; ushort* Xs = lds + 8192;
        const int p0 = (bid & 31) * 128, m0 = ((bid >> 5) & 7) * 128, bb = bid >> 8;
        const int wm = (w >> 1) * 64, wp = (w & 1) * 64;
        const ushort* Ag = Wallb + (size_t)m0 * 256;
        const ushort* Bg = xbfT + ((size_t)bb * 4096 + p0) * 256;
        f32x4 acc[4][4] = {};
        for (int ks = 0; ks < 4; ++ks) {
            stage_tile(Ag, 256, ks * 64, Ws, w, lane);
            stage_tile(Bg, 256, ks * 64, Xs, w, lane);
            __syncthreads();
            MFMA_STEP(Ws, Xs, wm, wp);
            __syncthreads();
        }
        #pragma unroll
        for (int fp = 0; fp < 4; ++fp) {
            const int p = p0 + wp + fp * 16 + i16;
            #pragma unroll
            for (int fm = 0; fm < 4; ++fm) {
                const int m = m0 + wm + fm * 16 + 4 * g;
                if (m0 < 256) {
                    ushort4 v;
                    v.x = f2bf(acc[fm][fp][0] * ATTN_SCALE); v.y = f2bf(acc[fm][fp][1] * ATTN_SCALE);
                    v.z = f2bf(acc[fm][fp][2] * ATTN_SCALE); v.w = f2bf(acc[fm][fp][3] * ATTN_SCALE);
                    *(ushort4*)&qTb[((size_t)bb * 4096 + p) * 256 + m] = v;
                } else if (m0 < 512) {
                    ushort4 v;
                    v.x = f2bf(acc[fm][fp][0]); v.y = f2bf(acc[fm][fp][1]);
                    v.z = f2bf(acc[fm][fp][2]); v.w = f2bf(acc[fm][fp][3]);
                    *(ushort4*)&qbT[((size_t)bb * 4096 + p) * 256 + (m - 256)] = v;
                } else {
                    ushort4 v;
                    v.x = f2bf(acc[fm][fp][0]); v.y = f2bf(acc[fm][fp][1]);
                    v.z = f2bf(acc[fm][fp][2]); v.w = f2bf(acc[fm][fp][3]);
                    *(ushort4*)&kvbT[((size_t)bb * 4096 + p) * 512 + (m - 512)] = v;
                }
            }
        }
    } else {
        // ---------------- conv branch ----------------
        ushort* Ws = lds;          // 64 rows x 64
        ushort* Xs = lds + 4096;   // 128 rows x 64
        const int id = bid - 1024;
        const int pp0 = (id & 7) * 128, m0 = ((id >> 3) & 7) * 64, bb = id >> 6;
        const int wm = (w >> 1) * 32, wp = (w & 1) * 64;
        const ushort* Ag = Wkvbb + (size_t)m0 * 1024;
        const ushort* Bg = xcol + ((size_t)bb * 1024 + pp0) * 1024;
        f32x4 acc[2][4] = {};
        for (int ks = 0; ks < 16; ++ks) {
            stage_tile_n<2>(Ag, 1024, ks * 64, Ws, w, lane);
            stage_tile_n<4>(Bg, 1024, ks * 64, Xs, w, lane);
            __syncthreads();
            #pragma unroll
            for (int kh = 0; kh < 2; ++kh) {
                bf16x8 av[2], bvv[4];
                #pragma unroll
                for (int fm = 0; fm < 2; ++fm) av[fm]  = frag_ld(Ws, wm + fm * 16 + i16, kh * 4 + g);
                #pragma unroll
                for (int fp = 0; fp < 4; ++fp) bvv[fp] = frag_ld(Xs, wp + fp * 16 + i16, kh * 4 + g);
                #pragma unroll
                for (int fm = 0; fm < 2; ++fm)
                    #pragma unroll
                    for (int fp = 0; fp < 4; ++fp)
                        acc[fm][fp] = __builtin_amdgcn_mfma_f32_16x16x32_bf16(av[fm], bvv[fp],
                                                                              acc[fm][fp], 0, 0, 0);
            }
            __syncthreads();
        }
        if (m0 < 256) {
            #pragma unroll
            for (int fp = 0; fp < 4; ++fp) {
                const int pp = pp0 + wp + fp * 16 + i16;
                #pragma unroll
                for (int fm = 0; fm < 2; ++fm) {
                    const int m = m0 + wm + fm * 16 + 4 * g;
                    ushort4 v;
                    v.x = f2bf(acc[fm][fp][0]); v.y = f2bf(acc[fm][fp][1]);
                    v.z = f2bf(acc[fm][fp][2]); v.w = f2bf(acc[fm][fp][3]);
                    *(ushort4*)&kTb[((size_t)bb * 1024 + pp) * 256 + m] = v;
                }
            }
        } else {
            // transpose 64(m) x 128(pp) through LDS, then coalesced rows out
            ushort (*T)[128] = (ushort(*)[128])lds;
            #pragma unroll
            for (int fm = 0; fm < 2; ++fm)
                #pragma unroll
                for (int fp = 0; fp < 4; ++fp)
                    #pragma unroll
                    for (int r = 0; r < 4; ++r)
                        T[wm + fm * 16 + 4 * g + r][wp + fp * 16 + i16] = f2bf(acc[fm][fp][r]);
            __syncthreads();
            #pragma unroll
            for (int u = 0; u < 4; ++u) {
                const int chunk = u * 256 + tid;
                const int row = chunk >> 4, slot = chunk & 15;
                const int mg = m0 - 256 + row;
                const int hh = mg >> 5, cc = mg & 31;
                const uint4 val = *(uint4*)&T[row][slot * 8];
                *(uint4*)&vTtb[((size_t)(bb * 8 + hh) * 32 + cc) * 1024 + pp0 + slot * 8] = val;
            }
        }
    }
}

// ---------------------------------------------------------------------------
// out_mfma: out[b][o][p] = sum_c Wout[o][c]*(sumT[b][p][c]+obT[b][p][c]).
// ---------------------------------------------------------------------------
__global__ __launch_bounds__(256) void out_mfma(
    const float* __restrict__ sumT, const ushort* __restrict__ obT,
    const ushort* __restrict__ Woutb, float* __restrict__ out)
{
    __shared__ __align__(16) ushort lds[16384];
    ushort* Ss = lds; ushort* Wo = lds + 8192;
    const int tid = threadIdx.x, lane = tid & 63, w = tid >> 6;
    const int g = lane >> 4, i16 = lane & 15;
    const int p0 = blockIdx.x * 128, o0 = blockIdx.y * 128, bb = blockIdx.z;
    const int wpp = (w >> 1) * 64, wo = (w & 1) * 64;
    const float* Sg = sumT + ((size_t)bb * 4096 + p0) * 256;
    const ushort* Og = obT + ((size_t)bb * 4096 + p0) * 256;
    const ushort* Bgw = Woutb + (size_t)o0 * 256;
    const int srow = tid >> 1, shalf = tid & 1;
    f32x4 acc[4][4] = {};
    for (int ks = 0; ks < 4; ++ks) {
        {   // reg-stage A: (fp32 sumT + bf16 obT) -> bf16, swizzled ds_write
            const float* src = Sg + (size_t)srow * 256 + ks * 64 + shalf * 32;
            const ushort* osrc = Og + (size_t)srow * 256 + ks * 64 + shalf * 32;
            #pragma unroll
            for (int jj = 0; jj < 4; ++jj) {
                const float4 f0 = *(const float4*)&src[jj * 8];
                const float4 f1 = *(const float4*)&src[jj * 8 + 4];
                const uint2 b0 = *(const uint2*)&osrc[jj * 8];
                const uint2 b1 = *(const uint2*)&osrc[jj * 8 + 4];
                uint4 pk;
                pk.x = pk2(f0.x + bf2f(b0.x & 0xffffu), f0.y + bf2f(b0.x >> 16));
                pk.y = pk2(f0.z + bf2f(b0.y & 0xffffu), f0.w + bf2f(b0.y >> 16));
                pk.z = pk2(f1.x + bf2f(b1.x & 0xffffu), f1.y + bf2f(b1.x >> 16));
                pk.w = pk2(f1.z + bf2f(b1.y & 0xffffu), f1.w + bf2f(b1.y >> 16));
                const int slog = shalf * 4 + jj;
                const int sp = slog ^ (srow & 7);
                *(uint4*)&Ss[(size_t)srow * 64 + sp * 8] = pk;
            }
        }
        stage_tile(Bgw, 256, ks * 64, Wo, w, lane);
        __syncthreads();
        MFMA_STEP(Ss, Wo, wpp, wo);
        __syncthreads();
    }
    #pragma unroll
    for (int fo = 0; fo < 4; ++fo) {
        const int o = o0 + wo + fo * 16 + i16;
        #pragma unroll
        for (int fp = 0; fp < 4; ++fp) {
            const int p = p0 + wpp + fp * 16 + 4 * g;
            const float4 v = make_float4(acc[fp][fo][0], acc[fp][fo][1],
                                         acc[fp][fo][2], acc[fp][fo][3]);
            *(float4*)&out[(size_t)bb * 1048576 + (size_t)o * 4096 + p] = v;
        }
    }
}

// ---------------------------------------------------------------------------
// attn_fused: blocks [0,1024) = attn_img (R4-exact body); [1024,1536) =
// attn_batch (LDS-staged, writes obT bf16). Default dispatch order (no XCD
// swizzle: R23 showed concentrating a K/V slab's 32 readers onto one XCD's
// L2 halves effective serving bandwidth; round-robin + L3 duplication wins).
// ---------------------------------------------------------------------------
__global__ __launch_bounds__(256) void attn_fused(
    const ushort* __restrict__ qTb, const ushort* __restrict__ kTb,
    const ushort* __restrict__ vTtb, const ushort* __restrict__ qbT,
    const ushort* __restrict__ kvbT, float* __restrict__ sumT,
    ushort* __restrict__ obT)
{
    __shared__ __align__(16) ushort smem[16704];
    const int bid = blockIdx.x;
    const int tid = threadIdx.x;

    if (bid < 1024) {
        // ================= attn_img branch (R4-exact) =================
        ushort (*Ks)[40]  = (ushort(*)[40])smem;
        ushort (*Vts)[136] = (ushort(*)[136])(smem + 5120);
        const int lane = tid & 63;
        const int wv   = tid >> 6;
        const int q    = lane & 31;
        const int hi   = lane >> 5;
        const int bh   = bid >> 5;
        const int b    = bh >> 3, h = bh & 7;
        const int q0   = (bid & 31) * 128 + wv * 32;

        bf16x8 qf[2];
        #pragma unroll
        for (int mm = 0; mm < 2; ++mm)
            qf[mm] = *(const bf16x8*)(qTb + ((size_t)(b * 4096 + q0 + q) * 256 + h * 32 + mm * 16 + hi * 8));

        f32x16 o = {};
        float mrun = -3.0e38f, lrun = 0.f;

        const ushort* kg = kTb + (size_t)b * 1024 * 256 + h * 32;
        const ushort* vg = vTtb + (size_t)bh * 32 * 1024;

        for (int kv0 = 0; kv0 < 1024; kv0 += 128) {
            __syncthreads();
            #pragma unroll
            for (int u = 0; u < 2; ++u) {
                const int chunk = tid + u * 256;
                const int r = chunk >> 2, q4 = chunk & 3;
                *(uint4*)&Ks[r][q4 * 8] = *(const uint4*)(kg + (size_t)(kv0 + r) * 256 + q4 * 8);
                const int c = chunk >> 4, sseg = chunk & 15;
                *(uint4*)&Vts[c][sseg * 8] = *(const uint4*)(vg + (size_t)c * 1024 + kv0 + sseg * 8);
            }
            __syncthreads();

            f32x16 s[4];
            #pragma unroll
            for (int t = 0; t < 4; ++t) {
                const bf16x8 k0 = *(const bf16x8*)&Ks[t * 32 + q][hi * 8];
                const bf16x8 k1 = *(const bf16x8*)&Ks[t * 32 + q][16 + hi * 8];
                f32x16 acc = {};
                acc = __builtin_amdgcn_mfma_f32_32x32x16_bf16(k0, qf[0], acc, 0, 0, 0);
                acc = __builtin_amdgcn_mfma_f32_32x32x16_bf16(k1, qf[1], acc, 0, 0, 0);
                s[t] = acc;
            }
            float pmax = -3.0e38f;
            #pragma unroll
            for (int t = 0; t < 4; ++t)
                #pragma unroll
                for (int r = 0; r < 16; ++r) pmax = fmaxf(pmax, s[t][r]);
            {
                float a_ = pmax, b_ = pmax;
                asm volatile("v_permlane32_swap_b32 %0, %1" : "+v"(a_), "+v"(b_));
                pmax = fmaxf(a_, b_);
            }
            const float mnew  = fmaxf(mrun, pmax);
            const float alpha = __expf(mrun - mnew);
            mrun = mnew;
            float ls = 0.f;
            #pragma unroll
            for (int t = 0; t < 4; ++t)
                #pragma unroll
                for (int r = 0; r < 16; ++r) {
                    const float p = __expf(s[t][r] - mnew);
                    s[t][r] = p; ls += p;
                }
            {
                float a_ = ls, b_ = ls;
                asm volatile("v_permlane32_swap_b32 %0, %1" : "+v"(a_), "+v"(b_));
                ls = a_ + b_;
            }
            lrun = lrun * alpha + ls;
            #pragma unroll
            for (int r = 0; r < 16; ++r) o[r] *= alpha;

            #pragma unroll
            for (int t = 0; t < 4; ++t) {
                unsigned int W[4][2];
                #pragma unroll
                for (int u = 0; u < 4; ++u) {
                    asm("v_cvt_pk_bf16_f32 %0, %1, %2"
                        : "=v"(W[u][0]) : "v"(s[t][4 * u + 0]), "v"(s[t][4 * u + 1]));
                    asm("v_cvt_pk_bf16_f32 %0, %1, %2"
                        : "=v"(W[u][1]) : "v"(s[t][4 * u + 2]), "v"(s[t][4 * u + 3]));
                }
                #pragma unroll
                for (int mm = 0; mm < 2; ++mm) {
                    unsigned int a0 = W[2 * mm][0], b0 = W[2 * mm + 1][0];
                    unsigned int a1 = W[2 * mm][1], b1 = W[2 * mm + 1][1];
                    asm volatile("v_permlane32_swap_b32 %0, %1" : "+v"(a0), "+v"(b0));
                    asm volatile("v_permlane32_swap_b32 %0, %1" : "+v"(a1), "+v"(b1));
                    unsigned int pw[4] = {a0, a1, b0, b1};
                    const bf16x8 pf = *(const bf16x8*)pw;
                    const bf16x8 vf = *(const bf16x8*)&Vts[q][t * 32 + mm * 16 + hi * 8];
                    o = __builtin_amdgcn_mfma_f32_32x32x16_bf16(vf, pf, o, 0, 0, 0);
                }
            }
        }

        const float inv = 1.f / lrun;
        float* dst = sumT + (size_t)(b * 4096 + q0 + q) * 256 + h * 32 + hi * 4;
        #pragma unroll
        for (int u = 0; u < 4; ++u) {
            const float4 v = make_float4(o[4 * u + 0] * inv, o[4 * u + 1] * inv,
                                         o[4 * u + 2] * inv, o[4 * u + 3] * inv);
            *(float4*)&dst[u * 8] = v;
        }
    } else {
        // ================= attn_batch branch (writes obT, no RMW) ===========
        ushort* kvs = smem;
        const int p0 = (bid - 1024) * 8;

        #pragma unroll
        for (int u = 0; u < 8; ++u) {
            const int c = u * 256 + tid;
            const int p = c >> 8;
            const int r = c & 255;
            const int b2 = r >> 6, seg = r & 63;
            const uint4 val = *(const uint4*)(kvbT + ((size_t)(b2 * 4096 + p0 + p)) * 512 + seg * 8);
            *(uint4*)&kvs[p * 2088 + b2 * 520 + seg * 8] = val;
        }
        __syncthreads();

        const int b1 = tid & 3, h = (tid >> 2) & 7, pl = tid >> 5;
        const int p = p0 + pl;
        const ushort* kvp = kvs + pl * 2088;

        const uint4* q4p = (const uint4*)(qbT + ((size_t)b1 * 4096 + p) * 256 + h * 32);
        float q[32];
        #pragma unroll
        for (int i = 0; i < 4; ++i) {
            const uint4 t = q4p[i];
            q[8 * i + 0] = bf2f(t.x & 0xffffu) * ATTN_SCALE; q[8 * i + 1] = bf2f(t.x >> 16) * ATTN_SCALE;
            q[8 * i + 2] = bf2f(t.y & 0xffffu) * ATTN_SCALE; q[8 * i + 3] = bf2f(t.y >> 16) * ATTN_SCALE;
            q[8 * i + 4] = bf2f(t.z & 0xffffu) * ATTN_SCALE; q[8 * i + 5] = bf2f(t.z >> 16) * ATTN_SCALE;
            q[8 * i + 6] = bf2f(t.w & 0xffffu) * ATTN_SCALE; q[8 * i + 7] = bf2f(t.w >> 16) * ATTN_SCALE;
        }

        float s[4];
        #pragma unroll
        for (int b2 = 0; b2 < 4; ++b2) {
            const uint4* k4 = (const uint4*)(kvp + b2 * 520 + h * 32);
            float d = 0.f;
            #pragma unroll
            for (int i = 0; i < 4; ++i) {
                const uint4 w = k4[i];
                d += q[8 * i + 0] * bf2f(w.x & 0xffffu) + q[8 * i + 1] * bf2f(w.x >> 16);
                d += q[8 * i + 2] * bf2f(w.y & 0xffffu) + q[8 * i + 3] * bf2f(w.y >> 16);
                d += q[8 * i + 4] * bf2f(w.z & 0xffffu) + q[8 * i + 5] * bf2f(w.z >> 16);
                d += q[8 * i + 6] * bf2f(w.w & 0xffffu) + q[8 * i + 7] * bf2f(w.w >> 16);
            }
            s[b2] = d;
        }
        const float mx = fmaxf(fmaxf(s[0], s[1]), fmaxf(s[2], s[3]));
        float w[4];
        float lsum = 0.f;
        #pragma unroll
        for (int b2 = 0; b2 < 4; ++b2) { w[b2] = __expf(s[b2] - mx); lsum += w[b2]; }
        const float inv = 1.f / lsum;
        #pragma unroll
        for (int b2 = 0; b2 < 4; ++b2) w[b2] *= inv;

        float acc[32] = {};
        #pragma unroll
        for (int b2 = 0; b2 < 4; ++b2) {
            const uint4* v4 = (const uint4*)(kvp + b2 * 520 + 256 + h * 32);
            const float wb = w[b2];
            #pragma unroll
            for (int i = 0; i < 4; ++i) {
                const uint4 vv = v4[i];
                acc[8 * i + 0] += wb * bf2f(vv.x & 0xffffu); acc[8 * i + 1] += wb * bf2f(vv.x >> 16);
                acc[8 * i + 2] += wb * bf2f(vv.y & 0xffffu); acc[8 * i + 3] += wb * bf2f(vv.y >> 16);
                acc[8 * i + 4] += wb * bf2f(vv.z & 0xffffu); acc[8 * i + 5] += wb * bf2f(vv.z >> 16);
                acc[8 * i + 6] += wb * bf2f(vv.w & 0xffffu); acc[8 * i + 7] += wb * bf2f(vv.w >> 16);
            }
        }
        uint4* o4 = (uint4*)(obT + ((size_t)b1 * 4096 + p) * 256 + h * 32);
        #pragma unroll
        for (int i = 0; i < 4; ++i) {
            uint4 r;
            r.x = pk2(acc[8 * i + 0], acc[8 * i + 1]);
            r.y = pk2(acc[8 * i + 2], acc[8 * i + 3]);
            r.z = pk2(acc[8 * i + 4], acc[8 * i + 5]);
            r.w = pk2(acc[8 * i + 6], acc[8 * i + 7]);
            o4[i] = r;
        }
    }
}

// ---------------------------------------------------------------------------
extern "C" void kernel_launch(void* const* d_in, const int* in_sizes, int n_in,
                              void* d_out, int out_size, void* d_ws, size_t ws_size,
                              hipStream_t stream)
{
    const float* x    = (const float*)d_in[0];
    const float* Wq   = (const float*)d_in[1];
    const float* Wkv  = (const float*)d_in[2];
    const float* Wqb  = (const float*)d_in[3];
    const float* Wkvb = (const float*)d_in[4];
    const float* Wout = (const float*)d_in[5];
    float* out = (float*)d_out;

    // workspace (ushort units). sumT (fp32, 16.78MB) aliases xbfT+xcol.
    // obT (bf16, 8.4MB) appended: total 56.2 MB.
    ushort* base  = (ushort*)d_ws;
    ushort* xbfT  = base;                    // 4,194,304
    ushort* xcol  = base + 4194304;          // 4,194,304
    ushort* Wallb = base + 8388608;          //   262,144
    ushort* Wkvbb = base + 8650752;          //   524,288
    float*  sumT  = (float*)base;            // aliases [0, 8388608) ushorts
    ushort* qTb   = base + 9175040;          // 4,194,304
    ushort* kvbT  = base + 13369344;         // 8,388,608
    ushort* kTb   = base + 21757952;         // 1,048,576
    ushort* vTtb  = base + 22806528;         // 1,048,576
    ushort* Woutb = base + 23855104;         //    65,536
    ushort* obT   = base + 23920640;         // 4,194,304 (bf16 batch-branch out)
    ushort* qbT   = (ushort*)out;            // d_out reused as qb scratch (bf16)

    cvt_fused<<<dim3(1344), 256, 0, stream>>>(x, Wq, Wqb, Wkvb, Wkv, Wout,
                                              xbfT, xcol, Wallb, Wkvbb, Woutb);
    projconv_fused<<<dim3(1280), 256, 0, stream>>>(Wallb, xbfT, Wkvbb, xcol,
                                                   qTb, qbT, kvbT, kTb, vTtb);
    attn_fused<<<dim3(1536), 256, 0, stream>>>(qTb, kTb, vTtb, qbT, kvbT, sumT, obT);
    out_mfma<<<dim3(32, 2, 4), 256, 0, stream>>>(sumT, obT, Woutb, out);
}